// Round 1
// baseline (268.874 us; speedup 1.0000x reference)
//
#include <hip/hip_runtime.h>

// Spline2D fused single-pass kernel, v3: drop the tmpl LDS staging stage.
// Block = 256 threads covers 16 rows (4096 floats) of one image.
// Fast path (block-uniform, ~65% of blocks): 4x nontemporal float4 zero stores.
// Slow path:
//   step1: rb[slot][k] = sum_i wx[i]*coeffs[r+2+i][k+2]   (1088 elems, LDS 5 KB)
//   store: each thread blends its 4 output float4s DIRECTLY from rb in
//          registers (only ~17/64 lanes per row touch LDS), then nt-stores.
// vs v2: one barrier instead of two, 20.25 KB -> 5 KB LDS, ~4x fewer LDS ops
// per slow block (the 16 KB tmpl round-trip is gone).

#define CW 72   // coeffs leading dim (64 + 2*4)

typedef float f4 __attribute__((ext_vector_type(4)));

__device__ __forceinline__ void st_nt(float* p, f4 v) {
    __builtin_nontemporal_store(v, reinterpret_cast<f4*>(p));
}

__global__ __launch_bounds__(256) void spline2d_fused3(
    const float* __restrict__ coeffs,
    const float* __restrict__ x,
    const float* __restrict__ y,
    float* __restrict__ out)
{
    __shared__ float rb[16][80];     // row-blended coeffs, 5 KB (stride 80: 16-lane
                                     // write groups land 16 banks apart -> <=2-way)

    const int blk    = blockIdx.x;
    const int b      = blk >> 4;     // image index (block-uniform)
    const int seg    = blk & 15;     // 16-row segment within image
    const int Rstart = seg << 4;

    const float xv = x[b];           // block-uniform -> scalar load
    const float fx = floorf(xv);
    const int   R0 = (int)fx + 96;   // patch top row in output

    const int t         = threadIdx.x;
    const int rowInPass = t >> 6;        // 0..3 (wave-uniform)
    const int col4      = (t & 63) << 2; // 0,4,...,252

    float* __restrict__ obase =
        out + ((size_t)b << 16) + ((size_t)Rstart << 8);
    const f4 z4 = {0.f, 0.f, 0.f, 0.f};

    // Block-uniform: does this 16-row segment intersect patch rows [R0, R0+64]?
    if (R0 > Rstart + 15 || R0 + 64 < Rstart) {
#pragma unroll
        for (int u = 0; u < 4; ++u)
            st_nt(obase + (u << 10) + (rowInPass << 8) + col4, z4);
        return;
    }

    // ---- slow path ----
    const float yv = y[b];
    const float fy = floorf(yv);
    const int   C0 = (int)fy + 96;   // patch left col in output
    const float sx = xv - fx, sy = yv - fy;

    float wx0, wx1, wx2, wx3, wy0, wy1, wy2, wy3;
    {
        const float p = sx, p2 = p * p, p3 = p2 * p, q = 1.0f - p;
        wx0 = p3 * (1.0f / 6.0f);
        wx1 = -0.5f * p3 + 0.5f * p2 + 0.5f * p + (1.0f / 6.0f);
        wx2 = 0.5f * p3 - p2 + (2.0f / 3.0f);
        wx3 = q * q * q * (1.0f / 6.0f);
    }
    {
        const float p = sy, p2 = p * p, p3 = p2 * p, q = 1.0f - p;
        wy0 = p3 * (1.0f / 6.0f);
        wy1 = -0.5f * p3 + 0.5f * p2 + 0.5f * p + (1.0f / 6.0f);
        wy2 = 0.5f * p3 - p2 + (2.0f / 3.0f);
        wy3 = q * q * q * (1.0f / 6.0f);
    }

    // step1: row blend. 16 threads per slot, 5 strided k-steps (no int div).
    {
        const int slot   = t >> 4;       // 0..15
        const int lane16 = t & 15;
        const int r      = Rstart + slot - R0;   // patch row index
        const bool rok   = (unsigned)r <= 64u;
        const float* p0base = coeffs + (r + 2) * CW + 2;
#pragma unroll
        for (int it = 0; it < 5; ++it) {
            const int k = lane16 + (it << 4);    // 0..67 (+pad skipped)
            if (k < 68) {
                float v = 0.0f;
                if (rok) {
                    const float* p0 = p0base + k;
                    v = p0[0] * wx0 + p0[CW] * wx1 + p0[2 * CW] * wx2 + p0[3 * CW] * wx3;
                }
                rb[slot][k] = v;
            }
        }
    }
    __syncthreads();

    // store phase: blend columns straight out of rb, nt-store float4s.
    const int c0 = col4 - C0;            // patch col of this thread's element 0
#pragma unroll
    for (int u = 0; u < 4; ++u) {
        const int slot = (u << 2) + rowInPass;
        const int r    = Rstart + slot - R0;
        f4 v = z4;
        if ((unsigned)r <= 64u && c0 >= -3 && c0 <= 64) {
#pragma unroll
            for (int m = 0; m < 4; ++m) {
                const int c = c0 + m;
                if ((unsigned)c <= 64u) {
                    v[m] = rb[slot][c] * wy0 + rb[slot][c + 1] * wy1 +
                           rb[slot][c + 2] * wy2 + rb[slot][c + 3] * wy3;
                }
            }
        }
        st_nt(obase + (u << 10) + (rowInPass << 8) + col4, v);
    }
}

extern "C" void kernel_launch(void* const* d_in, const int* in_sizes, int n_in,
                              void* d_out, int out_size, void* d_ws, size_t ws_size,
                              hipStream_t stream) {
    const float* coeffs = (const float*)d_in[0];  // (72,72)
    const float* x      = (const float*)d_in[1];  // (1024,)
    const float* y      = (const float*)d_in[2];  // (1024,)
    float* out = (float*)d_out;                   // (1024,1,256,256)

    const int batch = in_sizes[1];                // 1024
    spline2d_fused3<<<batch * 16, 256, 0, stream>>>(coeffs, x, y, out);
}